// Round 1
// baseline (530.713 us; speedup 1.0000x reference)
//
#include <hip/hip_runtime.h>
#include <math.h>

// Problem constants (from reference): B=64, N_total=1029, D=768, r=64, E=4, TOPK=1
// M_TOT = 64*1029 = 65856 tokens; MoE tokens = 64*1024 = 65536.

#define GELU(v) (0.5f*(v)*(1.0f + erff((v)*0.70710678118654752440f)))

// ---------------------------------------------------------------------------
// Kernel 1: h[m][j] = gelu( sum_k x[m][k] * Wd[j][k] ),  M=65856, N=64, K=768
// Block: 256 threads, tile 64 tokens x 64 outputs, K-tile 64.
// As natural [m][k] (float4 loads, conflict-free). Bs transposed [k][j] with
// xor swizzle on the column (4-float groups) so both the transpose stores and
// the inner-loop b128 reads are <=2-way (free).
// ---------------------------------------------------------------------------
__global__ __launch_bounds__(256) void k1_proj_gelu(
    const float* __restrict__ x, const float* __restrict__ Wd,
    float* __restrict__ h)
{
    __shared__ float As[64][68];
    __shared__ float Bs[64][68];
    const int tid = threadIdx.x;
    const int bm  = blockIdx.x;
    const int tm4 = (tid >> 4) << 2;
    const int tn4 = (tid & 15) << 2;
    const float* xblk = x + (size_t)bm * 64 * 768;

    float acc[4][4];
    #pragma unroll
    for (int i = 0; i < 4; ++i)
        #pragma unroll
        for (int j = 0; j < 4; ++j) acc[i][j] = 0.f;

    for (int kt = 0; kt < 768; kt += 64) {
        #pragma unroll
        for (int p = 0; p < 4; ++p) {
            int li = p*1024 + tid*4;
            int m = li >> 6, k = li & 63;
            float4 v = *(const float4*)(xblk + m*768 + kt + k);
            *(float4*)&As[m][k] = v;
        }
        #pragma unroll
        for (int p = 0; p < 4; ++p) {
            int li = p*1024 + tid*4;
            int j = li >> 6, k = li & 63;
            float4 v = *(const float4*)(Wd + j*768 + kt + k);
            int c = j ^ (((k >> 2) & 7) << 2);
            Bs[k+0][c] = v.x; Bs[k+1][c] = v.y; Bs[k+2][c] = v.z; Bs[k+3][c] = v.w;
        }
        __syncthreads();
        #pragma unroll
        for (int kk = 0; kk < 64; kk += 4) {
            const int swz = ((kk >> 2) & 7) << 2;
            float4 av[4], bv[4];
            #pragma unroll
            for (int i = 0; i < 4; ++i) av[i] = *(const float4*)&As[tm4 + i][kk];
            #pragma unroll
            for (int r = 0; r < 4; ++r) bv[r] = *(const float4*)&Bs[kk + r][tn4 ^ swz];
            #pragma unroll
            for (int i = 0; i < 4; ++i) {
                acc[i][0] += av[i].x*bv[0].x; acc[i][1] += av[i].x*bv[0].y;
                acc[i][2] += av[i].x*bv[0].z; acc[i][3] += av[i].x*bv[0].w;
                acc[i][0] += av[i].y*bv[1].x; acc[i][1] += av[i].y*bv[1].y;
                acc[i][2] += av[i].y*bv[1].z; acc[i][3] += av[i].y*bv[1].w;
                acc[i][0] += av[i].z*bv[2].x; acc[i][1] += av[i].z*bv[2].y;
                acc[i][2] += av[i].z*bv[2].z; acc[i][3] += av[i].z*bv[2].w;
                acc[i][0] += av[i].w*bv[3].x; acc[i][1] += av[i].w*bv[3].y;
                acc[i][2] += av[i].w*bv[3].z; acc[i][3] += av[i].w*bv[3].w;
            }
        }
        __syncthreads();
    }
    #pragma unroll
    for (int i = 0; i < 4; ++i) {
        int token = bm*64 + tm4 + i;
        float4 o;
        o.x = GELU(acc[i][0]); o.y = GELU(acc[i][1]);
        o.z = GELU(acc[i][2]); o.w = GELU(acc[i][3]);
        *(float4*)(h + (size_t)token*64 + tn4) = o;
    }
}

// ---------------------------------------------------------------------------
// Kernel 2: per MoE token (pos >= 5 within each row of 1029):
//   logits_e = t . Wg[e]; p = softmax; e* = argmax (top-1); w = p[e*]
//   full = t + w * (We[e*] . t + be[e*])    (in-place update of h)
// One wave per token, 4 waves/block, 64 tokens/block, grid 1024.
// We staged transposed in LDS with stride 65 (conflict-free scalar reads).
// ---------------------------------------------------------------------------
__global__ __launch_bounds__(256) void k2_moe(
    const float* __restrict__ Wg, const float* __restrict__ We,
    const float* __restrict__ be, float* __restrict__ h)
{
    __shared__ float sWg[4*64];
    __shared__ float sBe[4*64];
    __shared__ float sWeT[4*64*65];   // [e][r_in=k][s] stride 65
    __shared__ float sT[4][64];
    const int tid = threadIdx.x;

    for (int i = tid; i < 4*64; i += 256) { sWg[i] = Wg[i]; sBe[i] = be[i]; }
    for (int i = tid; i < 4*64*64; i += 256) {
        int e = i >> 12, rem = i & 4095, s = rem >> 6, k = rem & 63;
        sWeT[(e*64 + k)*65 + s] = We[i];
    }
    __syncthreads();

    const int wv = tid >> 6, lane = tid & 63;
    #pragma unroll 1
    for (int it = 0; it < 16; ++it) {
        int mt = blockIdx.x*64 + wv*16 + it;       // 0..65535
        int b = mt >> 10, n = mt & 1023;
        int token = b*1029 + 5 + n;
        float t = h[(size_t)token*64 + lane];

        float l0 = t * sWg[      lane];
        float l1 = t * sWg[ 64 + lane];
        float l2 = t * sWg[128 + lane];
        float l3 = t * sWg[192 + lane];
        #pragma unroll
        for (int off = 32; off > 0; off >>= 1) {
            l0 += __shfl_xor(l0, off);
            l1 += __shfl_xor(l1, off);
            l2 += __shfl_xor(l2, off);
            l3 += __shfl_xor(l3, off);
        }
        int ei = 0; float lm = l0;
        if (l1 > lm) { lm = l1; ei = 1; }
        if (l2 > lm) { lm = l2; ei = 2; }
        if (l3 > lm) { lm = l3; ei = 3; }
        float s = expf(l0 - lm) + expf(l1 - lm) + expf(l2 - lm) + expf(l3 - lm);
        float w = 1.0f / s;   // top-1 softmax weight (TEMPERATURE=1)

        sT[wv][lane] = t;     // wave-local staging; no cross-wave sharing
        float o = sBe[ei*64 + lane];
        const float* wp = &sWeT[(ei*64)*65 + lane];
        #pragma unroll 8
        for (int k = 0; k < 64; ++k)
            o += sT[wv][k] * wp[k*65];

        h[(size_t)token*64 + lane] = t + w * o;
    }
}

// ---------------------------------------------------------------------------
// Kernel 3: out[m][d] = gamma[d] * sum_k full[m][k] * Wu[d][k]
// M=65856, N=768, K=64. Block tile 64 tokens x 128 d. Grid (1029, 6).
// ---------------------------------------------------------------------------
__global__ __launch_bounds__(256) void k3_up_gamma(
    const float* __restrict__ h, const float* __restrict__ Wu,
    const float* __restrict__ gamma, float* __restrict__ out)
{
    __shared__ float Fs[64][68];    // natural [m][k]
    __shared__ float Ws[64][132];   // transposed [k][d], xor-swizzled cols
    const int tid = threadIdx.x;
    const int bm = blockIdx.x, bn = blockIdx.y;
    const int tm4 = (tid >> 4) << 2;
    const int tn8 = (tid & 15) << 3;

    #pragma unroll
    for (int p = 0; p < 4; ++p) {
        int li = p*1024 + tid*4;
        int m = li >> 6, k = li & 63;
        *(float4*)&Fs[m][k] = *(const float4*)(h + (size_t)(bm*64 + m)*64 + k);
    }
    #pragma unroll
    for (int p = 0; p < 8; ++p) {
        int li = p*1024 + tid*4;
        int dl = li >> 6, k = li & 63;
        float4 v = *(const float4*)(Wu + (size_t)(bn*128 + dl)*64 + k);
        int c = dl ^ (((k >> 2) & 7) << 2);
        Ws[k+0][c] = v.x; Ws[k+1][c] = v.y; Ws[k+2][c] = v.z; Ws[k+3][c] = v.w;
    }
    __syncthreads();

    float acc[4][8];
    #pragma unroll
    for (int i = 0; i < 4; ++i)
        #pragma unroll
        for (int j = 0; j < 8; ++j) acc[i][j] = 0.f;

    #pragma unroll
    for (int kk = 0; kk < 64; kk += 4) {
        const int swz = ((kk >> 2) & 7) << 2;
        float4 av[4], blo[4], bhi[4];
        #pragma unroll
        for (int i = 0; i < 4; ++i) av[i] = *(const float4*)&Fs[tm4 + i][kk];
        #pragma unroll
        for (int r = 0; r < 4; ++r) {
            blo[r] = *(const float4*)&Ws[kk + r][ tn8      ^ swz];
            bhi[r] = *(const float4*)&Ws[kk + r][(tn8 + 4) ^ swz];
        }
        #pragma unroll
        for (int i = 0; i < 4; ++i) {
            float a0 = av[i].x, a1 = av[i].y, a2 = av[i].z, a3 = av[i].w;
            acc[i][0] += a0*blo[0].x; acc[i][1] += a0*blo[0].y; acc[i][2] += a0*blo[0].z; acc[i][3] += a0*blo[0].w;
            acc[i][4] += a0*bhi[0].x; acc[i][5] += a0*bhi[0].y; acc[i][6] += a0*bhi[0].z; acc[i][7] += a0*bhi[0].w;
            acc[i][0] += a1*blo[1].x; acc[i][1] += a1*blo[1].y; acc[i][2] += a1*blo[1].z; acc[i][3] += a1*blo[1].w;
            acc[i][4] += a1*bhi[1].x; acc[i][5] += a1*bhi[1].y; acc[i][6] += a1*bhi[1].z; acc[i][7] += a1*bhi[1].w;
            acc[i][0] += a2*blo[2].x; acc[i][1] += a2*blo[2].y; acc[i][2] += a2*blo[2].z; acc[i][3] += a2*blo[2].w;
            acc[i][4] += a2*bhi[2].x; acc[i][5] += a2*bhi[2].y; acc[i][6] += a2*bhi[2].z; acc[i][7] += a2*bhi[2].w;
            acc[i][0] += a3*blo[3].x; acc[i][1] += a3*blo[3].y; acc[i][2] += a3*blo[3].z; acc[i][3] += a3*blo[3].w;
            acc[i][4] += a3*bhi[3].x; acc[i][5] += a3*bhi[3].y; acc[i][6] += a3*bhi[3].z; acc[i][7] += a3*bhi[3].w;
        }
    }

    float4 g0 = *(const float4*)(gamma + bn*128 + tn8);
    float4 g1 = *(const float4*)(gamma + bn*128 + tn8 + 4);
    #pragma unroll
    for (int i = 0; i < 4; ++i) {
        int token = bm*64 + tm4 + i;
        float4 o0, o1;
        o0.x = acc[i][0]*g0.x; o0.y = acc[i][1]*g0.y; o0.z = acc[i][2]*g0.z; o0.w = acc[i][3]*g0.w;
        o1.x = acc[i][4]*g1.x; o1.y = acc[i][5]*g1.y; o1.z = acc[i][6]*g1.z; o1.w = acc[i][7]*g1.w;
        float* op = out + (size_t)token*768 + bn*128 + tn8;
        *(float4*)op       = o0;
        *(float4*)(op + 4) = o1;
    }
}

extern "C" void kernel_launch(void* const* d_in, const int* in_sizes, int n_in,
                              void* d_out, int out_size, void* d_ws, size_t ws_size,
                              hipStream_t stream) {
    const float* x     = (const float*)d_in[0];
    const float* Wd    = (const float*)d_in[1];
    const float* Wg    = (const float*)d_in[2];
    const float* We    = (const float*)d_in[3];
    const float* be    = (const float*)d_in[4];
    const float* Wu    = (const float*)d_in[5];
    const float* gamma = (const float*)d_in[6];
    float* out = (float*)d_out;
    float* h   = (float*)d_ws;    // 65856*64 f32 = 16.9 MB scratch

    k1_proj_gelu<<<1029, 256, 0, stream>>>(x, Wd, h);
    k2_moe<<<1024, 256, 0, stream>>>(Wg, We, be, h);
    k3_up_gamma<<<dim3(1029, 6), 256, 0, stream>>>(h, Wu, gamma, out);
}